// Round 1
// baseline (1385.915 us; speedup 1.0000x reference)
//
#include <hip/hip_runtime.h>
#include <cstdint>
#include <cstddef>

#define T_TOK 2048
#define H_DIM 2048
#define E_NUM 8
#define F_DIM 4096

typedef __attribute__((ext_vector_type(8))) short bh8;    // 8 bf16 (4 VGPRs)
typedef __attribute__((ext_vector_type(4))) float f32x4;  // MFMA C/D

static __device__ __forceinline__ unsigned short f2bf(float f) {
  union { float f; unsigned int u; } v; v.f = f;
  unsigned int r = v.u + 0x7FFFu + ((v.u >> 16) & 1u);  // RNE
  return (unsigned short)(r >> 16);
}

// ---------------- x fp32 -> bf16 ----------------
__global__ __launch_bounds__(256) void convert_x(const float* __restrict__ x,
                                                 unsigned short* __restrict__ xb) {
  size_t i = ((size_t)blockIdx.x * 256 + threadIdx.x) * 4;
  float4 v = *(const float4*)(x + i);
  ushort4 o;
  o.x = f2bf(v.x); o.y = f2bf(v.y); o.z = f2bf(v.z); o.w = f2bf(v.w);
  *(ushort4*)(xb + i) = o;
}

// ---------------- gating + top-2 routing ----------------
__global__ __launch_bounds__(64) void gate_topk(const float* __restrict__ x,
                                                const float* __restrict__ gw,
                                                int* __restrict__ counts,
                                                int* __restrict__ etok,
                                                float* __restrict__ ewts) {
  const int t = blockIdx.x;
  const int lane = threadIdx.x;
  float acc[E_NUM];
#pragma unroll
  for (int e = 0; e < E_NUM; e++) acc[e] = 0.f;
  const float* xr = x + (size_t)t * H_DIM;
  for (int i = lane; i < H_DIM; i += 64) {
    float xv = xr[i];
#pragma unroll
    for (int e = 0; e < E_NUM; e++) acc[e] += xv * gw[e * H_DIM + i];
  }
#pragma unroll
  for (int e = 0; e < E_NUM; e++) {
#pragma unroll
    for (int off = 32; off > 0; off >>= 1) acc[e] += __shfl_xor(acc[e], off, 64);
  }
  if (lane == 0) {
    int e0 = 0;
#pragma unroll
    for (int e = 1; e < E_NUM; e++) if (acc[e] > acc[e0]) e0 = e;  // strict >: lowest idx on tie
    int e1 = (e0 == 0) ? 1 : 0;
#pragma unroll
    for (int e = 0; e < E_NUM; e++) {
      if (e != e0 && acc[e] > acc[e1]) e1 = e;
    }
    // renormalized pair softmax: w0 = p0/(p0+p1) = 1/(1+exp(l1-l0)), l0 >= l1
    float z = __expf(acc[e1] - acc[e0]);
    float w0 = 1.f / (1.f + z);
    float w1v = z / (1.f + z);
    int p0 = atomicAdd(&counts[e0], 1);
    etok[e0 * T_TOK + p0] = t; ewts[e0 * T_TOK + p0] = w0;
    int p1 = atomicAdd(&counts[e1], 1);
    etok[e1 * T_TOK + p1] = t; ewts[e1 * T_TOK + p1] = w1v;
  }
}

// ---------------- exclusive scan of 8 counts ----------------
__global__ void scan_offsets(const int* __restrict__ counts, int* __restrict__ offsets) {
  if (threadIdx.x == 0 && blockIdx.x == 0) {
    int run = 0;
    for (int e = 0; e < E_NUM; e++) { offsets[e] = run; run += counts[e]; }
  }
}

// ---------------- GEMM1: inter = silu(x@W1^T) * (x@W3^T), per expert ----------------
// block tile 128(M) x 64(N) x 32(K); 4 waves as 2x2; wave tile 64x32 per output matrix
__global__ __launch_bounds__(256) void gemm1_swiglu(
    const unsigned short* __restrict__ xb,   // [T][H] bf16
    const float* __restrict__ w1,            // [E*F][H] fp32
    const float* __restrict__ w3,
    const int* __restrict__ counts, const int* __restrict__ offsets,
    const int* __restrict__ etok,
    unsigned short* __restrict__ inter)      // [4096][F] bf16, rows compacted per expert
{
  const int e = blockIdx.z, mt = blockIdx.y, nt = blockIdx.x;
  const int cnt = counts[e];
  const int rem = cnt - mt * 128;
  if (rem <= 0) return;
  const int tid = threadIdx.x;
  const int lane = tid & 63;
  const int wv = tid >> 6;

  __shared__ alignas(16) unsigned short As[128][40];
  __shared__ alignas(16) unsigned short B1s[64][40];
  __shared__ alignas(16) unsigned short B3s[64][40];

  // A staging: 128 rows x 32 cols bf16; each thread 2x 16B loads
  const int ar0 = tid >> 2;
  const int ar1 = 64 + (tid >> 2);
  const int ac8 = (tid & 3) * 8;
  const int tokbase = e * T_TOK + mt * 128;
  const int t0 = etok[tokbase + (ar0 < rem ? ar0 : rem - 1)];
  const int t1 = etok[tokbase + (ar1 < rem ? ar1 : rem - 1)];
  const unsigned short* a0p = xb + (size_t)t0 * H_DIM + ac8;
  const unsigned short* a1p = xb + (size_t)t1 * H_DIM + ac8;

  // B staging: 64 rows x 32 cols fp32 -> bf16; each thread 2x float4 per matrix
  const int br0 = tid >> 3;
  const int br1 = 32 + (tid >> 3);
  const int bc4 = (tid & 7) * 4;
  const size_t wrow0 = ((size_t)(e * F_DIM + nt * 64 + br0)) * H_DIM + bc4;
  const size_t wrow1 = ((size_t)(e * F_DIM + nt * 64 + br1)) * H_DIM + bc4;

  const int wm = (wv >> 1) * 64;
  const int wn = (wv & 1) * 32;
  const int mrow = lane & 15;
  const int qk = (lane >> 4) * 8;

  f32x4 acc1[4][2], acc3[4][2];
#pragma unroll
  for (int i = 0; i < 4; i++)
#pragma unroll
    for (int j = 0; j < 2; j++) { acc1[i][j] = (f32x4)(0.f); acc3[i][j] = (f32x4)(0.f); }

  for (int k0 = 0; k0 < H_DIM; k0 += 32) {
    *(uint4*)&As[ar0][ac8] = *(const uint4*)(a0p + k0);
    *(uint4*)&As[ar1][ac8] = *(const uint4*)(a1p + k0);
    {
      float4 v0 = *(const float4*)(w1 + wrow0 + k0);
      float4 v1 = *(const float4*)(w1 + wrow1 + k0);
      float4 u0 = *(const float4*)(w3 + wrow0 + k0);
      float4 u1 = *(const float4*)(w3 + wrow1 + k0);
      ushort4 o;
      o.x = f2bf(v0.x); o.y = f2bf(v0.y); o.z = f2bf(v0.z); o.w = f2bf(v0.w);
      *(ushort4*)&B1s[br0][bc4] = o;
      o.x = f2bf(v1.x); o.y = f2bf(v1.y); o.z = f2bf(v1.z); o.w = f2bf(v1.w);
      *(ushort4*)&B1s[br1][bc4] = o;
      o.x = f2bf(u0.x); o.y = f2bf(u0.y); o.z = f2bf(u0.z); o.w = f2bf(u0.w);
      *(ushort4*)&B3s[br0][bc4] = o;
      o.x = f2bf(u1.x); o.y = f2bf(u1.y); o.z = f2bf(u1.z); o.w = f2bf(u1.w);
      *(ushort4*)&B3s[br1][bc4] = o;
    }
    __syncthreads();
    bh8 a[4], b1[2], b3[2];
#pragma unroll
    for (int i = 0; i < 4; i++) a[i] = *(const bh8*)&As[wm + i * 16 + mrow][qk];
#pragma unroll
    for (int j = 0; j < 2; j++) {
      b1[j] = *(const bh8*)&B1s[wn + j * 16 + mrow][qk];
      b3[j] = *(const bh8*)&B3s[wn + j * 16 + mrow][qk];
    }
#pragma unroll
    for (int i = 0; i < 4; i++)
#pragma unroll
      for (int j = 0; j < 2; j++) {
        acc1[i][j] = __builtin_amdgcn_mfma_f32_16x16x32_bf16(a[i], b1[j], acc1[i][j], 0, 0, 0);
        acc3[i][j] = __builtin_amdgcn_mfma_f32_16x16x32_bf16(a[i], b3[j], acc3[i][j], 0, 0, 0);
      }
    __syncthreads();
  }

  const int off = offsets[e];
  const int quad = lane >> 4;
#pragma unroll
  for (int i = 0; i < 4; i++) {
#pragma unroll
    for (int r = 0; r < 4; r++) {
      int m = wm + i * 16 + quad * 4 + r;
      if (m < rem) {
        size_t rowbase = (size_t)(off + mt * 128 + m) * F_DIM + nt * 64 + wn + mrow;
#pragma unroll
        for (int j = 0; j < 2; j++) {
          float c1 = acc1[i][j][r], c3 = acc3[i][j][r];
          float s = c1 / (1.f + __expf(-c1));
          inter[rowbase + j * 16] = f2bf(s * c3);
        }
      }
    }
  }
}

// ---------------- GEMM2: out[t,:] += wgt * (inter_row @ W2_e) ----------------
// block tile 128(M) x 128(N) x 32(K); W2 is [K=F][N=H] -> transpose-stage into LDS
__global__ __launch_bounds__(256) void gemm2_scatter(
    const unsigned short* __restrict__ inter,  // [4096][F] bf16
    const float* __restrict__ w2,              // [E*F][H] fp32
    const int* __restrict__ counts, const int* __restrict__ offsets,
    const int* __restrict__ etok, const float* __restrict__ ewts,
    float* __restrict__ out)                   // [T][H] fp32, pre-zeroed
{
  const int e = blockIdx.z, mt = blockIdx.y, nt = blockIdx.x;
  const int cnt = counts[e];
  const int rem = cnt - mt * 128;
  if (rem <= 0) return;
  const int tid = threadIdx.x;
  const int lane = tid & 63;
  const int wv = tid >> 6;

  __shared__ alignas(16) unsigned short As[128][40];
  __shared__ alignas(16) unsigned short Bs[128][40];  // Bs[n][k] = W2[k][n]

  const int off = offsets[e];
  const int ar0 = tid >> 2;
  const int ar1 = 64 + (tid >> 2);
  const int ac8 = (tid & 3) * 8;
  const int g0 = off + mt * 128 + (ar0 < rem ? ar0 : rem - 1);
  const int g1 = off + mt * 128 + (ar1 < rem ? ar1 : rem - 1);
  const unsigned short* a0p = inter + (size_t)g0 * F_DIM + ac8;
  const unsigned short* a1p = inter + (size_t)g1 * F_DIM + ac8;

  // B: 32(k) x 128(n) fp32 tile; thread loads 4 float4 along n, scatters transposed
  const int bkr = tid >> 5;          // 0..7, +l*8 -> k row 0..31
  const int bc4 = (tid & 31) * 4;    // n 0..124

  const int wm = (wv >> 1) * 64;
  const int wn = (wv & 1) * 64;
  const int mrow = lane & 15;
  const int qk = (lane >> 4) * 8;

  f32x4 acc[4][4];
#pragma unroll
  for (int i = 0; i < 4; i++)
#pragma unroll
    for (int j = 0; j < 4; j++) acc[i][j] = (f32x4)(0.f);

  for (int k0 = 0; k0 < F_DIM; k0 += 32) {
    *(uint4*)&As[ar0][ac8] = *(const uint4*)(a0p + k0);
    *(uint4*)&As[ar1][ac8] = *(const uint4*)(a1p + k0);
#pragma unroll
    for (int l = 0; l < 4; l++) {
      int krow = bkr + l * 8;
      float4 v = *(const float4*)(w2 + ((size_t)(e * F_DIM + k0 + krow)) * H_DIM + nt * 128 + bc4);
      Bs[bc4 + 0][krow] = f2bf(v.x);
      Bs[bc4 + 1][krow] = f2bf(v.y);
      Bs[bc4 + 2][krow] = f2bf(v.z);
      Bs[bc4 + 3][krow] = f2bf(v.w);
    }
    __syncthreads();
    bh8 a[4], b[4];
#pragma unroll
    for (int i = 0; i < 4; i++) a[i] = *(const bh8*)&As[wm + i * 16 + mrow][qk];
#pragma unroll
    for (int j = 0; j < 4; j++) b[j] = *(const bh8*)&Bs[wn + j * 16 + mrow][qk];
#pragma unroll
    for (int i = 0; i < 4; i++)
#pragma unroll
      for (int j = 0; j < 4; j++)
        acc[i][j] = __builtin_amdgcn_mfma_f32_16x16x32_bf16(a[i], b[j], acc[i][j], 0, 0, 0);
    __syncthreads();
  }

  const int quad = lane >> 4;
#pragma unroll
  for (int i = 0; i < 4; i++) {
#pragma unroll
    for (int r = 0; r < 4; r++) {
      int m = wm + i * 16 + quad * 4 + r;
      if (m < rem) {
        int slot = e * T_TOK + mt * 128 + m;
        int t = etok[slot];
        float wgt = ewts[slot];
        float* orow = out + (size_t)t * H_DIM + nt * 128 + wn + mrow;
#pragma unroll
        for (int j = 0; j < 4; j++) atomicAdd(orow + j * 16, wgt * acc[i][j][r]);
      }
    }
  }
}

extern "C" void kernel_launch(void* const* d_in, const int* in_sizes, int n_in,
                              void* d_out, int out_size, void* d_ws, size_t ws_size,
                              hipStream_t stream) {
  const float* x  = (const float*)d_in[0];
  const float* gw = (const float*)d_in[1];
  const float* w1 = (const float*)d_in[2];
  const float* w2 = (const float*)d_in[3];
  const float* w3 = (const float*)d_in[4];
  float* out = (float*)d_out;

  char* ws = (char*)d_ws;
  int* counts   = (int*)(ws + 0);            // 32 B
  int* offsets  = (int*)(ws + 64);           // 32 B
  int* etok     = (int*)(ws + 128);          // 8*2048*4 = 64 KB
  float* ewts   = (float*)(ws + 128 + 65536);
  unsigned short* xb    = (unsigned short*)(ws + 256 * 1024);                 // 8 MB
  unsigned short* inter = (unsigned short*)(ws + 256 * 1024 + 8 * 1024 * 1024); // 32 MB

  hipMemsetAsync(counts, 0, 64, stream);
  hipMemsetAsync(d_out, 0, (size_t)T_TOK * H_DIM * sizeof(float), stream);

  convert_x<<<(T_TOK * H_DIM) / (256 * 4), 256, 0, stream>>>(x, xb);
  gate_topk<<<T_TOK, 64, 0, stream>>>(x, gw, counts, etok, ewts);
  scan_offsets<<<1, 64, 0, stream>>>(counts, offsets);
  gemm1_swiglu<<<dim3(F_DIM / 64, 16, E_NUM), 256, 0, stream>>>(xb, w1, w3, counts, offsets, etok, inter);
  gemm2_scatter<<<dim3(H_DIM / 128, 16, E_NUM), 256, 0, stream>>>(inter, w2, counts, offsets, etok, ewts, out);
}

// Round 2
// 1191.860 us; speedup vs baseline: 1.1628x; 1.1628x over previous
//
#include <hip/hip_runtime.h>
#include <cstdint>
#include <cstddef>

#define T_TOK 2048
#define H_DIM 2048
#define E_NUM 8
#define F_DIM 4096

typedef __attribute__((ext_vector_type(8))) short bh8;    // 8 bf16 (4 VGPRs)
typedef __attribute__((ext_vector_type(4))) float f32x4;  // MFMA C/D

static __device__ __forceinline__ unsigned short f2bf(float f) {
  union { float f; unsigned int u; } v; v.f = f;
  unsigned int r = v.u + 0x7FFFu + ((v.u >> 16) & 1u);  // RNE
  return (unsigned short)(r >> 16);
}

// ---------------- fp32 -> bf16 elementwise (x, w1, w3) ----------------
__global__ __launch_bounds__(256) void convert_f32_bf16(const float* __restrict__ src,
                                                        unsigned short* __restrict__ dst) {
  size_t i = ((size_t)blockIdx.x * 256 + threadIdx.x) * 4;
  float4 v = *(const float4*)(src + i);
  ushort4 o;
  o.x = f2bf(v.x); o.y = f2bf(v.y); o.z = f2bf(v.z); o.w = f2bf(v.w);
  *(ushort4*)(dst + i) = o;
}

// ---------------- W2 [E*F][H] fp32 -> W2t [E][H][F] bf16 ----------------
__global__ __launch_bounds__(256) void transpose_w2(const float* __restrict__ w2,
                                                    unsigned short* __restrict__ w2t) {
  // grid: (H/64, F/64, E)
  const int e = blockIdx.z;
  const int f0 = blockIdx.y * 64;
  const int h0 = blockIdx.x * 64;
  __shared__ float tile[64][65];
  const int tid = threadIdx.x;
  const int r = tid >> 4;          // 0..15
  const int c4 = (tid & 15) * 4;   // 0..60
#pragma unroll
  for (int l = 0; l < 4; l++) {
    int f = r + l * 16;
    float4 v = *(const float4*)(w2 + ((size_t)(e * F_DIM + f0 + f)) * H_DIM + h0 + c4);
    tile[f][c4 + 0] = v.x; tile[f][c4 + 1] = v.y; tile[f][c4 + 2] = v.z; tile[f][c4 + 3] = v.w;
  }
  __syncthreads();
#pragma unroll
  for (int l = 0; l < 4; l++) {
    int h = r + l * 16;
    ushort4 o;
    o.x = f2bf(tile[c4 + 0][h]);
    o.y = f2bf(tile[c4 + 1][h]);
    o.z = f2bf(tile[c4 + 2][h]);
    o.w = f2bf(tile[c4 + 3][h]);
    *(ushort4*)(w2t + ((size_t)e * H_DIM + h0 + h) * F_DIM + f0 + c4) = o;
  }
}

// ---------------- gating + top-2 routing ----------------
__global__ __launch_bounds__(64) void gate_topk(const float* __restrict__ x,
                                                const float* __restrict__ gw,
                                                int* __restrict__ counts,
                                                int* __restrict__ etok,
                                                float* __restrict__ ewts) {
  const int t = blockIdx.x;
  const int lane = threadIdx.x;
  float acc[E_NUM];
#pragma unroll
  for (int e = 0; e < E_NUM; e++) acc[e] = 0.f;
  const float* xr = x + (size_t)t * H_DIM;
  for (int i = lane; i < H_DIM; i += 64) {
    float xv = xr[i];
#pragma unroll
    for (int e = 0; e < E_NUM; e++) acc[e] += xv * gw[e * H_DIM + i];
  }
#pragma unroll
  for (int e = 0; e < E_NUM; e++) {
#pragma unroll
    for (int off = 32; off > 0; off >>= 1) acc[e] += __shfl_xor(acc[e], off, 64);
  }
  if (lane == 0) {
    int e0 = 0;
#pragma unroll
    for (int e = 1; e < E_NUM; e++) if (acc[e] > acc[e0]) e0 = e;  // strict >: lowest idx on tie
    int e1 = (e0 == 0) ? 1 : 0;
#pragma unroll
    for (int e = 0; e < E_NUM; e++) {
      if (e != e0 && acc[e] > acc[e1]) e1 = e;
    }
    float z = __expf(acc[e1] - acc[e0]);
    float w0 = 1.f / (1.f + z);
    float w1v = z / (1.f + z);
    int p0 = atomicAdd(&counts[e0], 1);
    etok[e0 * T_TOK + p0] = t; ewts[e0 * T_TOK + p0] = w0;
    int p1 = atomicAdd(&counts[e1], 1);
    etok[e1 * T_TOK + p1] = t; ewts[e1 * T_TOK + p1] = w1v;
  }
}

// ---------------- exclusive scan of 8 counts ----------------
__global__ void scan_offsets(const int* __restrict__ counts, int* __restrict__ offsets) {
  if (threadIdx.x == 0 && blockIdx.x == 0) {
    int run = 0;
    for (int e = 0; e < E_NUM; e++) { offsets[e] = run; run += counts[e]; }
  }
}

// ---------------- GEMM1: inter = silu(x@W1^T) * (x@W3^T) ----------------
// block tile 128(M) x 64(N) x 32(K); 4 waves 2x2; wave tile 64x32 per matrix
template<bool BW>
__global__ __launch_bounds__(256) void gemm1_swiglu(
    const unsigned short* __restrict__ xb,
    const float* __restrict__ w1f, const float* __restrict__ w3f,
    const unsigned short* __restrict__ w1b, const unsigned short* __restrict__ w3b,
    const int* __restrict__ counts, const int* __restrict__ offsets,
    const int* __restrict__ etok,
    unsigned short* __restrict__ inter)
{
  const int e = blockIdx.z, mt = blockIdx.y, nt = blockIdx.x;
  const int rem = counts[e] - mt * 128;
  if (rem <= 0) return;
  const int tid = threadIdx.x;
  const int lane = tid & 63;
  const int wv = tid >> 6;

  __shared__ alignas(16) unsigned short As[128][40];
  __shared__ alignas(16) unsigned short B1s[64][40];
  __shared__ alignas(16) unsigned short B3s[64][40];

  const int ar0 = tid >> 2, ar1 = 64 + (tid >> 2);
  const int ac8 = (tid & 3) * 8;
  const int tokbase = e * T_TOK + mt * 128;
  const int t0 = etok[tokbase + (ar0 < rem ? ar0 : rem - 1)];
  const int t1 = etok[tokbase + (ar1 < rem ? ar1 : rem - 1)];
  const unsigned short* a0p = xb + (size_t)t0 * H_DIM + ac8;
  const unsigned short* a1p = xb + (size_t)t1 * H_DIM + ac8;

  const int wm = (wv >> 1) * 64;
  const int wn = (wv & 1) * 32;
  const int mrow = lane & 15;
  const int qk = (lane >> 4) * 8;

  f32x4 acc1[4][2], acc3[4][2];
#pragma unroll
  for (int i = 0; i < 4; i++)
#pragma unroll
    for (int j = 0; j < 2; j++) { acc1[i][j] = (f32x4)(0.f); acc3[i][j] = (f32x4)(0.f); }

  for (int k0 = 0; k0 < H_DIM; k0 += 32) {
    *(uint4*)&As[ar0][ac8] = *(const uint4*)(a0p + k0);
    *(uint4*)&As[ar1][ac8] = *(const uint4*)(a1p + k0);
    if constexpr (BW) {
      const int br = tid >> 2;          // 0..63
      const int bc8 = (tid & 3) * 8;
      size_t wrow = ((size_t)(e * F_DIM + nt * 64 + br)) * H_DIM + bc8 + k0;
      *(uint4*)&B1s[br][bc8] = *(const uint4*)(w1b + wrow);
      *(uint4*)&B3s[br][bc8] = *(const uint4*)(w3b + wrow);
    } else {
      const int br0 = tid >> 3, br1 = 32 + (tid >> 3);
      const int bc4 = (tid & 7) * 4;
      size_t wrow0 = ((size_t)(e * F_DIM + nt * 64 + br0)) * H_DIM + bc4 + k0;
      size_t wrow1 = ((size_t)(e * F_DIM + nt * 64 + br1)) * H_DIM + bc4 + k0;
      float4 v0 = *(const float4*)(w1f + wrow0);
      float4 v1 = *(const float4*)(w1f + wrow1);
      float4 u0 = *(const float4*)(w3f + wrow0);
      float4 u1 = *(const float4*)(w3f + wrow1);
      ushort4 o;
      o.x = f2bf(v0.x); o.y = f2bf(v0.y); o.z = f2bf(v0.z); o.w = f2bf(v0.w);
      *(ushort4*)&B1s[br0][bc4] = o;
      o.x = f2bf(v1.x); o.y = f2bf(v1.y); o.z = f2bf(v1.z); o.w = f2bf(v1.w);
      *(ushort4*)&B1s[br1][bc4] = o;
      o.x = f2bf(u0.x); o.y = f2bf(u0.y); o.z = f2bf(u0.z); o.w = f2bf(u0.w);
      *(ushort4*)&B3s[br0][bc4] = o;
      o.x = f2bf(u1.x); o.y = f2bf(u1.y); o.z = f2bf(u1.z); o.w = f2bf(u1.w);
      *(ushort4*)&B3s[br1][bc4] = o;
    }
    __syncthreads();
    bh8 a[4], b1[2], b3[2];
#pragma unroll
    for (int i = 0; i < 4; i++) a[i] = *(const bh8*)&As[wm + i * 16 + mrow][qk];
#pragma unroll
    for (int j = 0; j < 2; j++) {
      b1[j] = *(const bh8*)&B1s[wn + j * 16 + mrow][qk];
      b3[j] = *(const bh8*)&B3s[wn + j * 16 + mrow][qk];
    }
#pragma unroll
    for (int i = 0; i < 4; i++)
#pragma unroll
      for (int j = 0; j < 2; j++) {
        acc1[i][j] = __builtin_amdgcn_mfma_f32_16x16x32_bf16(a[i], b1[j], acc1[i][j], 0, 0, 0);
        acc3[i][j] = __builtin_amdgcn_mfma_f32_16x16x32_bf16(a[i], b3[j], acc3[i][j], 0, 0, 0);
      }
    __syncthreads();
  }

  const int off = offsets[e];
  const int quad = lane >> 4;
#pragma unroll
  for (int i = 0; i < 4; i++) {
#pragma unroll
    for (int r = 0; r < 4; r++) {
      int m = wm + i * 16 + quad * 4 + r;
      if (m < rem) {
        size_t rowbase = (size_t)(off + mt * 128 + m) * F_DIM + nt * 64 + wn + mrow;
#pragma unroll
        for (int j = 0; j < 2; j++) {
          float c1 = acc1[i][j][r], c3 = acc3[i][j][r];
          float s = c1 / (1.f + __expf(-c1));
          inter[rowbase + j * 16] = f2bf(s * c3);
        }
      }
    }
  }
}

// ---------------- GEMM2: out[t,:] += wgt * (inter_row @ W2_e) ----------------
// block tile 128(M) x 128(N) x 32(K)
template<bool BW>
__global__ __launch_bounds__(256) void gemm2_scatter(
    const unsigned short* __restrict__ inter,  // [4096][F] bf16
    const float* __restrict__ w2f,             // [E*F][H] fp32 (fallback)
    const unsigned short* __restrict__ w2t,    // [E][H][F] bf16 (fast)
    const int* __restrict__ counts, const int* __restrict__ offsets,
    const int* __restrict__ etok, const float* __restrict__ ewts,
    float* __restrict__ out)                   // [T][H] fp32, pre-zeroed
{
  const int e = blockIdx.z, mt = blockIdx.y, nt = blockIdx.x;
  const int rem = counts[e] - mt * 128;
  if (rem <= 0) return;
  const int tid = threadIdx.x;
  const int lane = tid & 63;
  const int wv = tid >> 6;

  __shared__ alignas(16) unsigned short As[128][40];
  __shared__ alignas(16) unsigned short Bs[128][40];  // Bs[n][k]

  const int off = offsets[e];
  const int ar0 = tid >> 2, ar1 = 64 + (tid >> 2);
  const int ac8 = (tid & 3) * 8;
  const int g0 = off + mt * 128 + (ar0 < rem ? ar0 : rem - 1);
  const int g1 = off + mt * 128 + (ar1 < rem ? ar1 : rem - 1);
  const unsigned short* a0p = inter + (size_t)g0 * F_DIM + ac8;
  const unsigned short* a1p = inter + (size_t)g1 * F_DIM + ac8;

  const int wm = (wv >> 1) * 64;
  const int wn = (wv & 1) * 64;
  const int mrow = lane & 15;
  const int qk = (lane >> 4) * 8;

  f32x4 acc[4][4];
#pragma unroll
  for (int i = 0; i < 4; i++)
#pragma unroll
    for (int j = 0; j < 4; j++) acc[i][j] = (f32x4)(0.f);

  for (int k0 = 0; k0 < F_DIM; k0 += 32) {
    *(uint4*)&As[ar0][ac8] = *(const uint4*)(a0p + k0);
    *(uint4*)&As[ar1][ac8] = *(const uint4*)(a1p + k0);
    if constexpr (BW) {
      // w2t[e][n][k]: same copy pattern as A
      const unsigned short* bp0 = w2t + ((size_t)e * H_DIM + nt * 128 + ar0) * F_DIM + ac8;
      const unsigned short* bp1 = w2t + ((size_t)e * H_DIM + nt * 128 + ar1) * F_DIM + ac8;
      *(uint4*)&Bs[ar0][ac8] = *(const uint4*)(bp0 + k0);
      *(uint4*)&Bs[ar1][ac8] = *(const uint4*)(bp1 + k0);
    } else {
      const int bkr = tid >> 5;
      const int bc4 = (tid & 31) * 4;
#pragma unroll
      for (int l = 0; l < 4; l++) {
        int krow = bkr + l * 8;
        float4 v = *(const float4*)(w2f + ((size_t)(e * F_DIM + k0 + krow)) * H_DIM + nt * 128 + bc4);
        Bs[bc4 + 0][krow] = f2bf(v.x);
        Bs[bc4 + 1][krow] = f2bf(v.y);
        Bs[bc4 + 2][krow] = f2bf(v.z);
        Bs[bc4 + 3][krow] = f2bf(v.w);
      }
    }
    __syncthreads();
    bh8 a[4], b[4];
#pragma unroll
    for (int i = 0; i < 4; i++) a[i] = *(const bh8*)&As[wm + i * 16 + mrow][qk];
#pragma unroll
    for (int j = 0; j < 4; j++) b[j] = *(const bh8*)&Bs[wn + j * 16 + mrow][qk];
#pragma unroll
    for (int i = 0; i < 4; i++)
#pragma unroll
      for (int j = 0; j < 4; j++)
        acc[i][j] = __builtin_amdgcn_mfma_f32_16x16x32_bf16(a[i], b[j], acc[i][j], 0, 0, 0);
    __syncthreads();
  }

  const int quad = lane >> 4;
#pragma unroll
  for (int i = 0; i < 4; i++) {
#pragma unroll
    for (int r = 0; r < 4; r++) {
      int m = wm + i * 16 + quad * 4 + r;
      if (m < rem) {
        int slot = e * T_TOK + mt * 128 + m;
        int t = etok[slot];
        float wgt = ewts[slot];
        float* orow = out + (size_t)t * H_DIM + nt * 128 + wn + mrow;
#pragma unroll
        for (int j = 0; j < 4; j++) unsafeAtomicAdd(orow + j * 16, wgt * acc[i][j][r]);
      }
    }
  }
}

extern "C" void kernel_launch(void* const* d_in, const int* in_sizes, int n_in,
                              void* d_out, int out_size, void* d_ws, size_t ws_size,
                              hipStream_t stream) {
  const float* x  = (const float*)d_in[0];
  const float* gw = (const float*)d_in[1];
  const float* w1 = (const float*)d_in[2];
  const float* w2 = (const float*)d_in[3];
  const float* w3 = (const float*)d_in[4];
  float* out = (float*)d_out;

  char* ws = (char*)d_ws;
  int* counts   = (int*)(ws + 0);
  int* offsets  = (int*)(ws + 64);
  int* etok     = (int*)(ws + 128);                    // 64 KB
  float* ewts   = (float*)(ws + 128 + 65536);          // 64 KB
  unsigned short* xb    = (unsigned short*)(ws + 256 * 1024);                        // 8 MB
  unsigned short* inter = (unsigned short*)(ws + 256 * 1024 + 8 * 1024 * 1024);      // 32 MB
  const size_t BASE_END = 256 * 1024 + 8ull * 1024 * 1024 + 33554432ull;             // 42,205,184
  const size_t WB = (size_t)E_NUM * F_DIM * H_DIM * 2;                               // 128 MB each
  unsigned short* w2t = (unsigned short*)(ws + BASE_END);
  unsigned short* w1b = (unsigned short*)(ws + BASE_END + WB);
  unsigned short* w3b = (unsigned short*)(ws + BASE_END + 2 * WB);
  const size_t MID  = BASE_END + WB;       // w2t fits
  const size_t FULL = BASE_END + 3 * WB;   // + w1b,w3b
  const bool tA = ws_size >= MID;
  const bool tB = ws_size >= FULL;

  hipMemsetAsync(counts, 0, 64, stream);
  hipMemsetAsync(d_out, 0, (size_t)T_TOK * H_DIM * sizeof(float), stream);

  convert_f32_bf16<<<(T_TOK * H_DIM) / (256 * 4), 256, 0, stream>>>(x, xb);
  gate_topk<<<T_TOK, 64, 0, stream>>>(x, gw, counts, etok, ewts);
  scan_offsets<<<1, 64, 0, stream>>>(counts, offsets);

  const int WBLK = (E_NUM * F_DIM * H_DIM) / (256 * 4);  // 65536
  if (tB) {
    convert_f32_bf16<<<WBLK, 256, 0, stream>>>(w1, w1b);
    convert_f32_bf16<<<WBLK, 256, 0, stream>>>(w3, w3b);
  }
  if (tA) {
    transpose_w2<<<dim3(H_DIM / 64, F_DIM / 64, E_NUM), 256, 0, stream>>>(w2, w2t);
  }

  if (tB) {
    gemm1_swiglu<true><<<dim3(F_DIM / 64, 16, E_NUM), 256, 0, stream>>>(
        xb, w1, w3, w1b, w3b, counts, offsets, etok, inter);
  } else {
    gemm1_swiglu<false><<<dim3(F_DIM / 64, 16, E_NUM), 256, 0, stream>>>(
        xb, w1, w3, w1b, w3b, counts, offsets, etok, inter);
  }
  if (tA) {
    gemm2_scatter<true><<<dim3(H_DIM / 128, 16, E_NUM), 256, 0, stream>>>(
        inter, w2, w2t, counts, offsets, etok, ewts, out);
  } else {
    gemm2_scatter<false><<<dim3(H_DIM / 128, 16, E_NUM), 256, 0, stream>>>(
        inter, w2, w2t, counts, offsets, etok, ewts, out);
  }
}